// Round 4
// baseline (1980.239 us; speedup 1.0000x reference)
//
#include <hip/hip_runtime.h>
#include <hip/hip_bf16.h>
#include <stdint.h>

// SimpleRNN: B=64, S=512, H=1024, V=128
// Phase 1 (R18): seqlock exchange — sequence number EMBEDDED in the data.
//   Back to the PROVEN R15 structure (64 wgs = 2 batch-halves x 32 col-groups,
//   8-wave K-split, sc1/L3 exchange, triple-buffered h, LDS W + red).
//   Sync rewrite: each 8 B exchange unit = {u32 data (2 bf16 cols), u32 seq},
//   written by ONE global_store_dwordx2 (8 B single-copy atomic -> data+tag
//   cannot tear). Producer's store IS the publication (no vmcnt drain, no
//   flag store). Consumer's load IS the poll: load 16x16B units, validate all
//   32 seq words == epoch+s+1, retry on mismatch. Removes 2 of 3 L3 legs
//   from the per-step critical path. Exact-match validation enforces
//   triple-buffer safety; per-launch epoch (bumped in pack_wout) prevents
//   cross-launch aliasing. No flags, no init rendezvous, no workspace.
// Phase 2: logits GEMM (hidden bf16 @ W_out bf16, 32x32x16 MFMA) + b_out.

#define Bz 64
#define Sz 512
#define Hz 1024
#define Vz 128
#define NWG 64    // 2 batch-halves x 32 col-groups
#define COLS 32   // columns of W_hh per workgroup
#define WGT 512   // 8 waves = 8-way K-split (128 k each)

typedef __attribute__((ext_vector_type(8)))  short short8;
typedef __attribute__((ext_vector_type(16))) float f32x16;
typedef __attribute__((ext_vector_type(4)))  unsigned u32x4;   // asm-friendly 16B
typedef __attribute__((ext_vector_type(2)))  unsigned u32x2;   // asm-friendly 8B

__device__ unsigned g_epoch;    // bumped once per launch (pack_wout block0/tid0)

// seq-embedded h exchange, TRIPLE buffer:
// g_hx[gen][bh][kb=k>>4][lane=((k>>3)&1)*32+r][8 words]
//   words = {d0,q, d1,q, d2,q, d3,q}; dw = bf16 cols (2w, 2w+1) of k-octet,
//   q = epoch_base + step + 1.  (768 KB total, L3-resident)
__device__ __align__(16) unsigned g_hx[3][2][64][64][8];
// hidden states, fragment order per step: [s][bh][kb][lane][8]  (64 MB)
__device__ __align__(16) unsigned short g_hidden[(size_t)Sz*2*64*64*8];
// W_out packed for 32x32x16 B-frags: [kb][nt][lane][8]  (256 KB)
__device__ __align__(16) unsigned short g_wout[64*4*64*8];

__device__ __forceinline__ unsigned short f2bf(float f) {
  union { float f; unsigned u; } v; v.f = f;
  unsigned r = v.u + 0x7FFFu + ((v.u >> 16) & 1u);      // RNE
  return (unsigned short)(r >> 16);
}

__device__ __forceinline__ float fast_tanh(float x) {
  float cx = fminf(9.0f, fmaxf(-9.0f, x));
  float e  = __builtin_amdgcn_exp2f(cx * 2.88539008178f);   // e^(2x)
  return (e - 1.0f) * __builtin_amdgcn_rcpf(e + 1.0f);
}

// 16 L3-coherent 16-B loads covering this wave's 8 kb planes (2 units/plane),
// with the drain INSIDE the asm block (outputs valid on exit — no reorder
// hazard). Plane stride 2048 B; 4 base pointers x offsets {0,16,2048,2064}.
__device__ __forceinline__ void load16_seq(const unsigned* p0, u32x4 t[16]) {
  const unsigned* p1 = p0 + 1024;   // +4096 B (2 planes)
  const unsigned* p2 = p0 + 2048;
  const unsigned* p3 = p0 + 3072;
  asm volatile(
    "global_load_dwordx4 %0,  %16, off sc1\n\t"
    "global_load_dwordx4 %1,  %16, off offset:16 sc1\n\t"
    "global_load_dwordx4 %2,  %16, off offset:2048 sc1\n\t"
    "global_load_dwordx4 %3,  %16, off offset:2064 sc1\n\t"
    "global_load_dwordx4 %4,  %17, off sc1\n\t"
    "global_load_dwordx4 %5,  %17, off offset:16 sc1\n\t"
    "global_load_dwordx4 %6,  %17, off offset:2048 sc1\n\t"
    "global_load_dwordx4 %7,  %17, off offset:2064 sc1\n\t"
    "global_load_dwordx4 %8,  %18, off sc1\n\t"
    "global_load_dwordx4 %9,  %18, off offset:16 sc1\n\t"
    "global_load_dwordx4 %10, %18, off offset:2048 sc1\n\t"
    "global_load_dwordx4 %11, %18, off offset:2064 sc1\n\t"
    "global_load_dwordx4 %12, %19, off sc1\n\t"
    "global_load_dwordx4 %13, %19, off offset:16 sc1\n\t"
    "global_load_dwordx4 %14, %19, off offset:2048 sc1\n\t"
    "global_load_dwordx4 %15, %19, off offset:2064 sc1\n\t"
    "s_waitcnt vmcnt(0)"
    : "=&v"(t[0]), "=&v"(t[1]), "=&v"(t[2]),  "=&v"(t[3]),
      "=&v"(t[4]), "=&v"(t[5]), "=&v"(t[6]),  "=&v"(t[7]),
      "=&v"(t[8]), "=&v"(t[9]), "=&v"(t[10]), "=&v"(t[11]),
      "=&v"(t[12]),"=&v"(t[13]),"=&v"(t[14]), "=&v"(t[15])
    : "v"(p0), "v"(p1), "v"(p2), "v"(p3)
    : "memory");
}

// 8 B single-instruction store (single-copy atomic unit {data, seq})
__device__ __forceinline__ void store8_sc1(unsigned* p, u32x2 v) {
  asm volatile("global_store_dwordx2 %0, %1, off sc1" :: "v"(p), "v"(v) : "memory");
}

// ---- Phase 0: pack W_out (H,V) fp32 -> [kb][nt][lane][8] bf16 (32x32 B-frag) --
__global__ void pack_wout(const float* __restrict__ W_out) {
  if (blockIdx.x == 0 && threadIdx.x == 0) g_epoch = g_epoch + 1u;  // per-launch
  int gid = blockIdx.x * blockDim.x + threadIdx.x;      // 0..16383
  int lane = gid & 63;
  int nt   = (gid >> 6) & 3;
  int kb   = gid >> 8;
  int n = nt * 32 + (lane & 31);
  int k0 = kb * 16 + (lane >> 5) * 8;
  unsigned short t[8];
#pragma unroll
  for (int j = 0; j < 8; ++j)
    t[j] = f2bf(W_out[(size_t)(k0 + j) * Vz + n]);
  uint4 w;
  w.x = (unsigned)t[0] | ((unsigned)t[1] << 16);
  w.y = (unsigned)t[2] | ((unsigned)t[3] << 16);
  w.z = (unsigned)t[4] | ((unsigned)t[5] << 16);
  w.w = (unsigned)t[6] | ((unsigned)t[7] << 16);
  *(uint4*)&g_wout[(size_t)gid * 8] = w;
}

// ---------------- Phase 1: persistent recurrence -----------------------------
__global__ __launch_bounds__(WGT) void rnn_persistent(
    const int* __restrict__ x, const float* __restrict__ h0,
    const float* __restrict__ W_xh, const float* __restrict__ W_hh,
    const float* __restrict__ b_h, float* __restrict__ out)
{
  // W slice (32 cols): [kb(64)][lane=kq*32+n][8] -> B-frag via ds_read_b128
  __shared__ unsigned short ldsW[64 * 64 * 8];          // 64 KB
  // 8 K-split partial regions, XOR-swizzled: red[ki*1024 + m*32 + (c^m)]
  __shared__ float red[8 * 1024];                       // 32 KB
  // 96 KB total -> 1 wg per CU (proven R14/R15 configuration)

  const int g    = blockIdx.x;        // 0..63
  const int bh   = g >> 5;            // batch half (rows bh*32 .. +32)
  const int cg   = g & 31;            // col-group
  const int n0g  = cg * COLS;         // global column base of W slice
  const int tid  = threadIdx.x;
  const int lane = tid & 63;
  const int ki   = tid >> 6;          // wave = K-split 0..7 (128 k each)
  const int bn   = lane & 31;
  const unsigned epb = g_epoch << 10; // epoch base (seq namespace per launch)

  // ---- stage W_hh[:, n0g : n0g+32) -> ldsW (one-time) ----
  for (int idx = tid; idx < 64 * 64; idx += WGT) {
    int kb = idx >> 6, L = idx & 63;
    int n = L & 31, kq = L >> 5;
    unsigned short t[8];
#pragma unroll
    for (int j = 0; j < 8; ++j)
      t[j] = f2bf(W_hh[(size_t)(kb * 16 + kq * 8 + j) * Hz + n0g + n]);
    uint4 w;
    w.x = (unsigned)t[0] | ((unsigned)t[1] << 16);
    w.y = (unsigned)t[2] | ((unsigned)t[3] << 16);
    w.z = (unsigned)t[4] | ((unsigned)t[5] << 16);
    w.w = (unsigned)t[6] | ((unsigned)t[7] << 16);
    *(uint4*)&ldsW[(size_t)idx * 8] = w;
  }

  // ---- h0 -> g_hx[0] with seq = epb+1; wg g stages units [g*512, +512) ----
  {
    int u  = g * 512 + tid;           // unit = {4B data, 4B seq}
    int w  = u & 3;                   // word-pair within (kb,lane)
    int L  = (u >> 2) & 63;
    int kb = (u >> 8) & 63;
    int fb = (u >> 14) & 1;           // batch half
    int m  = fb * 32 + (L & 31);
    int k  = kb * 16 + (L >> 5) * 8 + w * 2;
    const float* src = &h0[(size_t)m * Hz + k];
    u32x2 v;
    v.x = (unsigned)f2bf(src[0]) | ((unsigned)f2bf(src[1]) << 16);
    v.y = epb + 1u;
    store8_sc1(&g_hx[0][fb][kb][L][2 * w], v);
  }
  __syncthreads();        // ldsW ready; h0 visibility enforced by seq-retry

  // epilogue mapping: 512 threads -> 32 rows x 16 col-pairs
  const int er   = tid & 31;                  // row within batch half
  const int em   = bh * 32 + er;              // global batch row
  const int c0   = (tid >> 5) * 2;            // col within wg slice (even)
  const int kcol = n0g + c0;                  // global h column
  const int kb_g = kcol >> 4;
  const int kq2  = (kcol >> 3) & 1;
  const int lslot = kq2 * 32 + er;
  const int wq   = (c0 >> 1) & 3;             // unit index within (kb,lane)
  unsigned* exw0 = &g_hx[0][bh][kb_g][lslot][2 * wq];   // + gen*65536 u32s
  const size_t hidOff =
      ((((size_t)bh * 64) + kb_g) * 64 + lslot) * 8 + (kcol & 7);
  const float bias0 = b_h[kcol], bias1 = b_h[kcol + 1];

  // prefetch step-0 token + embedding pair
  int tok_n = x[em * Sz];
  float2 xv_n = *(const float2*)&W_xh[(size_t)tok_n * Hz + kcol];

  int rp = 0;                               // read generation = s % 3
  for (int s = 0; s < Sz; ++s) {
    const int wp = (rp == 2) ? 0 : rp + 1;  // write generation
    const unsigned tgt = epb + (unsigned)(s + 1);   // expected seq this step

    // fused poll+load: retry full 16-unit load until ALL 32 seq words match.
    u32x4 t[16];
    {
      const unsigned* hp = &g_hx[rp][bh][ki * 8][lane][0];
      const int bound = (s == 0) ? 65536 : 8192;
      for (int it = 0; it < bound; ++it) {
        load16_seq(hp, t);                  // includes s_waitcnt vmcnt(0)
        unsigned bad = (t[0].y ^ tgt) | (t[0].w ^ tgt);
#pragma unroll
        for (int i = 1; i < 16; ++i)
          bad |= (t[i].y ^ tgt) | (t[i].w ^ tgt);
        if (__all(bad == 0u)) break;
        __builtin_amdgcn_s_sleep(1);
      }
      asm volatile("" ::: "memory");
    }

    // MFMA over this wave's 8 kb planes; A-frags extracted from data words.
    f32x16 acc0 = {}, acc1 = {};
#pragma unroll
    for (int p = 0; p < 8; p += 2) {
      u32x4 fa, fb2;
      fa.x  = t[2 * p].x;     fa.y  = t[2 * p].z;
      fa.z  = t[2 * p + 1].x; fa.w  = t[2 * p + 1].z;
      fb2.x = t[2 * p + 2].x; fb2.y = t[2 * p + 2].z;
      fb2.z = t[2 * p + 3].x; fb2.w = t[2 * p + 3].z;
      const int kbp = ki * 8 + p;
      short8 ba = *(const short8*)&ldsW[(size_t)(kbp * 64 + lane) * 8];
      short8 bb = *(const short8*)&ldsW[(size_t)((kbp + 1) * 64 + lane) * 8];
      acc0 = __builtin_amdgcn_mfma_f32_32x32x16_bf16(*(short8*)&fa, ba,
                                                     acc0, 0, 0, 0);
      acc1 = __builtin_amdgcn_mfma_f32_32x32x16_bf16(*(short8*)&fb2, bb,
                                                     acc1, 0, 0, 0);
    }

    // prefetch NEXT step's token + embedding pair (hides gather latency)
    float2 xv = xv_n;
    if (s + 1 < Sz) {
      int t2 = x[em * Sz + s + 1];
      xv_n = *(const float2*)&W_xh[(size_t)t2 * Hz + kcol];
    }

    __syncthreads();     // BAR-A: prev step's epilogue done reading red
    // C/D: col=lane&31, row=(reg&3)+8*(reg>>2)+4*(lane>>5)  [m74/m101]
    {
#pragma unroll
      for (int r = 0; r < 16; ++r) {
        int m = 4 * (lane >> 5) + (r & 3) + 8 * (r >> 2);
        red[ki * 1024 + m * 32 + (bn ^ m)] = acc0[r] + acc1[r];
      }
    }
    __syncthreads();     // BAR-B: all 8 partials in red

    // epilogue: z = sum of 8 partials + emb + bias; h = tanh(z)
    float z0, z1;
    {
      const int o0 = er * 32 + (c0 ^ er);
      const int o1 = er * 32 + ((c0 + 1) ^ er);
      z0 = ((red[o0] + red[1024 + o0]) + (red[2048 + o0] + red[3072 + o0])) +
           ((red[4096 + o0] + red[5120 + o0]) + (red[6144 + o0] + red[7168 + o0]));
      z1 = ((red[o1] + red[1024 + o1]) + (red[2048 + o1] + red[3072 + o1])) +
           ((red[4096 + o1] + red[5120 + o1]) + (red[6144 + o1] + red[7168 + o1]));
    }
    z0 = fast_tanh(z0 + xv.x + bias0);
    z1 = fast_tanh(z1 + xv.y + bias1);

    unsigned w2 = (unsigned)f2bf(z0) | ((unsigned)f2bf(z1) << 16);

    // publication = the data store itself: {data, seq} in one 8 B atomic unit.
    // No drain, no flag — consumers validate the embedded seq.
    u32x2 v; v.x = w2; v.y = epb + (unsigned)(s + 2);
    store8_sc1(exw0 + (size_t)wp * 65536, v);

    // off the critical path:
    *(unsigned*)&g_hidden[(size_t)s * 65536 + hidOff] = w2;
    if (s == Sz - 1) {
      float* hf = out + (size_t)Bz * Sz * Vz + (size_t)em * Hz + kcol;
      hf[0] = z0; hf[1] = z1;
    }
    rp = wp;
  }
}

// ---------------- Phase 2: logits = hidden @ W_out + b_out -------------------
// grid: 1024 blocks = (s, mi); 4 waves; wave nt computes 32 rows x 32 cols, K=1024
__global__ __launch_bounds__(256) void logits_gemm(
    const float* __restrict__ b_out, float* __restrict__ out)
{
  const int tid = threadIdx.x, lane = tid & 63, nt = tid >> 6;
  const int s = blockIdx.x >> 1, mi = blockIdx.x & 1;
  const unsigned short* ab = &g_hidden[((size_t)s * 8192 + (size_t)mi * 4096) * 8];

  f32x16 acc = {};
#pragma unroll 8
  for (int kb = 0; kb < 64; ++kb) {
    short8 a = *(const short8*)&ab[(size_t)(kb * 64 + lane) * 8];
    short8 b = *(const short8*)&g_wout[(size_t)((kb * 4 + nt) * 64 + lane) * 8];
    acc = __builtin_amdgcn_mfma_f32_32x32x16_bf16(a, b, acc, 0, 0, 0);
  }
  const int col = nt * 32 + (lane & 31);
  const float bo = b_out[col];
  const int rbase = 4 * (lane >> 5);
#pragma unroll
  for (int r = 0; r < 16; ++r) {
    int m = rbase + (r & 3) + 8 * (r >> 2);
    int em = mi * 32 + m;
    out[((size_t)em * Sz + s) * Vz + col] = acc[r] + bo;
  }
}

// ---------------- host launcher ----------------------------------------------
extern "C" void kernel_launch(void* const* d_in, const int* in_sizes, int n_in,
                              void* d_out, int out_size, void* d_ws, size_t ws_size,
                              hipStream_t stream) {
  const int*   x     = (const int*)d_in[0];
  const float* h0    = (const float*)d_in[1];
  const float* W_xh  = (const float*)d_in[2];
  const float* W_hh  = (const float*)d_in[3];
  const float* b_h   = (const float*)d_in[4];
  const float* W_out = (const float*)d_in[5];
  const float* b_out = (const float*)d_in[6];
  float* out = (float*)d_out;

  pack_wout<<<64, 256, 0, stream>>>(W_out);   // also bumps g_epoch
  rnn_persistent<<<NWG, WGT, 0, stream>>>(x, h0, W_xh, W_hh, b_h, out);
  logits_gemm<<<Sz * 2, 256, 0, stream>>>(b_out, out);
}